// Round 22
// baseline (466.629 us; speedup 1.0000x reference)
//
#include <hip/hip_runtime.h>

// ---------------------------------------------------------------------------
// Sparse MS-Deformable Attention, f32 (+f16 projected value maps).
// Round 22: 2-DEEP pipelined proj with NAMED double buffers (stA/stB,
// explicit x2-unrolled loop -- rule-#20-safe, unlike r6/r7's indexed
// rotations). r21 analysis: proj BW (3.9 TB/s) matches Little's law at
// ~65% load duty cycle x 20 waves/CU; 1-deep pipelining cannot raise the
// average outstanding bytes. 2-deep: each buffer's 8 loads issued a full
// loop body before consumption -> ~100% duty, 16 loads/wave in flight ->
// HBM-bound. Everything except proj byte-identical to r21 (best=453.8).
// ---------------------------------------------------------------------------

typedef float f32x4 __attribute__((ext_vector_type(4)));
typedef _Float16 f16;
typedef f16 f16x8 __attribute__((ext_vector_type(8)));
typedef f16 f16x4 __attribute__((ext_vector_type(4)));

// Y[n, 0:M] = X[n, 0:256] @ W[256, M] + bias ; 32 rows/block, M threads.
// Safe in-place (Y==X): block stages its 32 rows to LDS before any write.
template<int M>
__global__ __launch_bounds__(M)
void gemm_rb(const float* __restrict__ X, const float* __restrict__ W,
             const float* __restrict__ bias, float* __restrict__ Y) {
    __shared__ float xt[32 * 256];
    const int tid = threadIdx.x;
    const long row0 = (long)blockIdx.x * 32;
    const float4* src = (const float4*)(X + row0 * 256);
    float4* dst4 = (float4*)xt;
    for (int i = tid; i < 32 * 64; i += M) dst4[i] = src[i];
    __syncthreads();

    constexpr int CG = M / 4;
    const int cg = tid % CG, qg = tid / CG;
    const int c0 = cg * 4, q0 = qg * 8;

    f32x4 acc[8];
#pragma unroll
    for (int qi = 0; qi < 8; ++qi) acc[qi] = (f32x4){0.f, 0.f, 0.f, 0.f};

    for (int k4 = 0; k4 < 64; ++k4) {
        f32x4 w[4];
#pragma unroll
        for (int r = 0; r < 4; ++r)
            w[r] = *(const f32x4*)&W[(size_t)(k4 * 4 + r) * M + c0];
        f32x4 xv[8];
#pragma unroll
        for (int qi = 0; qi < 8; ++qi)
            xv[qi] = *(const f32x4*)&xt[(q0 + qi) * 256 + k4 * 4];
#pragma unroll
        for (int qi = 0; qi < 8; ++qi) {
            f32x4 a = acc[qi];
            const f32x4 x = xv[qi];
            a.x = fmaf(x.x, w[0].x, a.x); a.y = fmaf(x.x, w[0].y, a.y);
            a.z = fmaf(x.x, w[0].z, a.z); a.w = fmaf(x.x, w[0].w, a.w);
            a.x = fmaf(x.y, w[1].x, a.x); a.y = fmaf(x.y, w[1].y, a.y);
            a.z = fmaf(x.y, w[1].z, a.z); a.w = fmaf(x.y, w[1].w, a.w);
            a.x = fmaf(x.z, w[2].x, a.x); a.y = fmaf(x.z, w[2].y, a.y);
            a.z = fmaf(x.z, w[2].z, a.z); a.w = fmaf(x.z, w[2].w, a.w);
            a.x = fmaf(x.w, w[3].x, a.x); a.y = fmaf(x.w, w[3].y, a.y);
            a.z = fmaf(x.w, w[3].z, a.z); a.w = fmaf(x.w, w[3].w, a.w);
            acc[qi] = a;
        }
    }

    const f32x4 bv = *(const f32x4*)&bias[c0];
#pragma unroll
    for (int qi = 0; qi < 8; ++qi) {
        f32x4 o = acc[qi];
        o.x += bv.x; o.y += bv.y; o.z += bv.z; o.w += bv.w;
        *(f32x4*)&Y[(size_t)(row0 + q0 + qi) * M + c0] = o;
    }
}

// ---- fused query projections: Y1[n,0:256]=X@W_off+b_off,
//      Y2[n,0:128]=X@W_attn+b_attn. 32 rows/block, 384 threads.
__global__ __launch_bounds__(384)
void gemm_qproj(const float* __restrict__ X,
                const float* __restrict__ W_off, const float* __restrict__ b_off,
                const float* __restrict__ W_attn, const float* __restrict__ b_attn,
                float* __restrict__ Y1, float* __restrict__ Y2) {
    __shared__ float xt[32 * 260];
    const int tid = threadIdx.x;
    const long row0 = (long)blockIdx.x * 32;
    const float4* src = (const float4*)(X + row0 * 256);
    for (int i = tid; i < 32 * 64; i += 384) {
        const int r = i >> 6, c4 = i & 63;
        *(float4*)(xt + r * 260 + c4 * 4) = src[i];
    }
    __syncthreads();

    const int cg = tid % 96, qg = tid / 96;
    const int c0 = cg * 4, q0 = qg * 8;
    const bool off_part = (c0 < 256);
    const float* Wp = off_part ? (W_off + c0) : (W_attn + (c0 - 256));
    const float* bp = off_part ? (b_off + c0) : (b_attn + (c0 - 256));
    const int ldW = off_part ? 256 : 128;
    float* Yp = off_part ? (Y1 + c0) : (Y2 + (c0 - 256));

    f32x4 acc[8];
#pragma unroll
    for (int qi = 0; qi < 8; ++qi) acc[qi] = (f32x4){0.f, 0.f, 0.f, 0.f};

    for (int k4 = 0; k4 < 64; ++k4) {
        f32x4 w[4];
#pragma unroll
        for (int r = 0; r < 4; ++r)
            w[r] = *(const f32x4*)&Wp[(size_t)(k4 * 4 + r) * ldW];
        f32x4 xv[8];
#pragma unroll
        for (int qi = 0; qi < 8; ++qi)
            xv[qi] = *(const f32x4*)&xt[(q0 + qi) * 260 + k4 * 4];
#pragma unroll
        for (int qi = 0; qi < 8; ++qi) {
            f32x4 a = acc[qi];
            const f32x4 x = xv[qi];
            a.x = fmaf(x.x, w[0].x, a.x); a.y = fmaf(x.x, w[0].y, a.y);
            a.z = fmaf(x.x, w[0].z, a.z); a.w = fmaf(x.x, w[0].w, a.w);
            a.x = fmaf(x.y, w[1].x, a.x); a.y = fmaf(x.y, w[1].y, a.y);
            a.z = fmaf(x.y, w[1].z, a.z); a.w = fmaf(x.y, w[1].w, a.w);
            a.x = fmaf(x.z, w[2].x, a.x); a.y = fmaf(x.z, w[2].y, a.y);
            a.z = fmaf(x.z, w[2].z, a.z); a.w = fmaf(x.z, w[2].w, a.w);
            a.x = fmaf(x.w, w[3].x, a.x); a.y = fmaf(x.w, w[3].y, a.y);
            a.z = fmaf(x.w, w[3].z, a.z); a.w = fmaf(x.w, w[3].w, a.w);
            acc[qi] = a;
        }
    }

    const f32x4 bv = *(const f32x4*)bp;
#pragma unroll
    for (int qi = 0; qi < 8; ++qi) {
        f32x4 o = acc[qi];
        o.x += bv.x; o.y += bv.y; o.z += bv.z; o.w += bv.w;
        *(f32x4*)&Yp[(size_t)(row0 + q0 + qi) * ldW] = o;
    }
}

// ---- spatial binning ----
#define NBINS 4096

__device__ __forceinline__ int bin_of(float ri, float rj) {
    int bi = (int)ri >> 3, bj = (int)rj >> 3;
    bi = min(63, max(0, bi)); bj = min(63, max(0, bj));
    return bi * 64 + bj;
}

__global__ void bin_hist(const float* __restrict__ refp, int* __restrict__ hist, int N) {
    const int n = blockIdx.x * blockDim.x + threadIdx.x;
    if (n < N) atomicAdd(&hist[bin_of(refp[2 * n], refp[2 * n + 1])], 1);
}

__global__ __launch_bounds__(256)
void bin_scan(const int* __restrict__ hist, int* __restrict__ binptr) {
    __shared__ int part[256];
    const int t = threadIdx.x;
    int vals[16], excl[16], run = 0;
#pragma unroll
    for (int i = 0; i < 16; ++i) { vals[i] = hist[t * 16 + i]; }
#pragma unroll
    for (int i = 0; i < 16; ++i) { excl[i] = run; run += vals[i]; }
    part[t] = run;
    __syncthreads();
    int off = 0;
    for (int i = 0; i < t; ++i) off += part[i];
#pragma unroll
    for (int i = 0; i < 16; ++i) binptr[t * 16 + i] = off + excl[i];
}

__global__ void bin_scatter(const float* __restrict__ refp, int* __restrict__ binptr,
                            int* __restrict__ perm, int N) {
    const int n = blockIdx.x * blockDim.x + threadIdx.x;
    if (n < N) {
        const int b = bin_of(refp[2 * n], refp[2 * n + 1]);
        const int pos = atomicAdd(&binptr[b], 1);
        perm[pos] = n;
    }
}

// ---- W_val swizzle into MFMA-fragment order ----
__global__ __launch_bounds__(256)
void prep_wvF(const float* __restrict__ W, f16* __restrict__ wvF) {
    const int k = blockIdx.x, n = threadIdx.x;
    const int ks = k >> 5, kg = (k >> 3) & 3, j = k & 7;
    const int tile = n >> 4, l15 = n & 15;
    const int lane = (kg << 4) | l15;
    wvF[((size_t)(ks * 16 + tile) * 512) + lane * 8 + j] = (f16)W[(size_t)k * 256 + n];
}

// ---- 2-deep pipelined persistent proj, 32-px tiles, head-planar -----------
#define NT_PROJ 21760

__device__ __forceinline__
void proj_load_tile(int t, const float* __restrict__ v0, const float* __restrict__ v1,
                    const float* __restrict__ v2, const float* __restrict__ v3,
                    int wave, int lane, float4 (&st)[8]) {
    const float* V; long px0;
    if (t < 256)        { V = v0; px0 = (long)t * 32; }
    else if (t < 1280)  { V = v1; px0 = (long)(t - 256) * 32; }
    else if (t < 5376)  { V = v2; px0 = (long)(t - 1280) * 32; }
    else                { V = v3; px0 = (long)(t - 5376) * 32; }
#pragma unroll
    for (int i = 0; i < 8; ++i)
        st[i] = *(const float4*)(V + (px0 + wave + i * 4) * 256 + lane * 4);
}

__device__ __forceinline__
void proj_process(int t, int tnext,
                  const float* __restrict__ v0, const float* __restrict__ v1,
                  const float* __restrict__ v2, const float* __restrict__ v3,
                  const f16* __restrict__ wvF, const float* __restrict__ bval,
                  f16* __restrict__ vp0, f16* __restrict__ vp1,
                  f16* __restrict__ vp2, f16* __restrict__ vp3,
                  int wave, int lane, int l15, int kg, int tid,
                  float4 (&st)[8], f16 (*At)[264]) {
    // 1. convert staged regs -> LDS (vmcnt wait lands here)
    __syncthreads();   // prior copy-out done reading At
#pragma unroll
    for (int i = 0; i < 8; ++i) {
        const int px = wave + i * 4;
        f16x4 h4 = {(f16)st[i].x, (f16)st[i].y, (f16)st[i].z, (f16)st[i].w};
        *(f16x4*)(&At[px][lane * 4]) = h4;
    }
    __syncthreads();

    // 2. refill THIS buffer with tile t+2G; fence pins the loads here.
    if (tnext < NT_PROJ) {
        proj_load_tile(tnext, v0, v1, v2, v3, wave, lane, st);
        asm volatile("" ::: "memory");
    }

    // 3. MFMA
    f32x4 acc[2][4];
#pragma unroll
    for (int a = 0; a < 2; ++a)
#pragma unroll
        for (int b = 0; b < 4; ++b) acc[a][b] = (f32x4){0.f, 0.f, 0.f, 0.f};

#pragma unroll
    for (int ks = 0; ks < 8; ++ks) {
        f16x8 wf[4];
#pragma unroll
        for (int ct = 0; ct < 4; ++ct)
            wf[ct] = *(const f16x8*)(wvF + ((size_t)(ks * 16 + wave * 4 + ct) * 512) + lane * 8);
        f16x8 vf[2];
#pragma unroll
        for (int pt = 0; pt < 2; ++pt)
            vf[pt] = *(const f16x8*)(&At[pt * 16 + l15][ks * 32 + kg * 8]);
#pragma unroll
        for (int pt = 0; pt < 2; ++pt)
#pragma unroll
            for (int ct = 0; ct < 4; ++ct)
                acc[pt][ct] = __builtin_amdgcn_mfma_f32_16x16x32_f16(wf[ct], vf[pt], acc[pt][ct], 0, 0, 0);
    }

    // 4. acc + bias -> LDS
    __syncthreads();
#pragma unroll
    for (int ct = 0; ct < 4; ++ct) {
        const int chb = wave * 64 + ct * 16 + kg * 4;
        const float4 bv = *(const float4*)(bval + chb);
#pragma unroll
        for (int pt = 0; pt < 2; ++pt) {
            f16x4 o = {(f16)(acc[pt][ct].x + bv.x), (f16)(acc[pt][ct].y + bv.y),
                       (f16)(acc[pt][ct].z + bv.z), (f16)(acc[pt][ct].w + bv.w)};
            *(f16x4*)(&At[pt * 16 + l15][chb]) = o;
        }
    }
    __syncthreads();

    // 5. coalesced head-planar copy-out
    {
        f16* VP; long px0, hwsq;
        if (t < 256)        { VP = vp0; px0 = (long)t * 32;          hwsq = 4096;   }
        else if (t < 1280)  { VP = vp1; px0 = (long)(t - 256) * 32;  hwsq = 16384;  }
        else if (t < 5376)  { VP = vp2; px0 = (long)(t - 1280) * 32; hwsq = 65536;  }
        else                { VP = vp3; px0 = (long)(t - 5376) * 32; hwsq = 262144; }
        const long bt = (px0 >= hwsq) ? 1 : 0;
        const long pxb = px0 - bt * hwsq;
        f16* base = VP + (size_t)bt * hwsq * 256;
#pragma unroll
        for (int i = 0; i < 4; ++i) {
            const int c2 = i * 256 + tid;
            const int hh = c2 >> 7;
            const int rem = c2 & 127;
            const int px = rem >> 2;
            const int sub = rem & 3;
            *(f16x8*)(base + (size_t)hh * hwsq * 32 + (pxb + px) * 32 + sub * 8) =
                *(const f16x8*)(&At[px][hh * 32 + sub * 8]);
        }
    }
}

__global__ __launch_bounds__(256)
void proj_val_pipe2(const float* __restrict__ v0, const float* __restrict__ v1,
                    const float* __restrict__ v2, const float* __restrict__ v3,
                    const f16* __restrict__ wvF, const float* __restrict__ bval,
                    f16* __restrict__ vp0, f16* __restrict__ vp1,
                    f16* __restrict__ vp2, f16* __restrict__ vp3) {
    __shared__ f16 At[32][264];
    const int tid = threadIdx.x;
    const int wave = tid >> 6, lane = tid & 63;
    const int l15 = lane & 15, kg = lane >> 4;
    const int G = gridDim.x;

    const int t0 = blockIdx.x;
    if (t0 >= NT_PROJ) return;

    float4 stA[8], stB[8];
    proj_load_tile(t0, v0, v1, v2, v3, wave, lane, stA);
    if (t0 + G < NT_PROJ)
        proj_load_tile(t0 + G, v0, v1, v2, v3, wave, lane, stB);
    asm volatile("" ::: "memory");

    for (int t = t0; t < NT_PROJ; t += 2 * G) {
        proj_process(t, t + 2 * G, v0, v1, v2, v3, wvF, bval,
                     vp0, vp1, vp2, vp3, wave, lane, l15, kg, tid, stA, At);
        if (t + G < NT_PROJ)
            proj_process(t + G, t + 3 * G, v0, v1, v2, v3, wvF, bval,
                         vp0, vp1, vp2, vp3, wave, lane, l15, kg, tid, stB, At);
    }
}

// ---- gather from head-planar vp (byte-identical to r19/r20/r21) ------------
#define GQPB 4
__global__ __launch_bounds__(256)
void gather_vp(const float* __restrict__ offs_all,
               const float* __restrict__ logits_all,
               const float* __restrict__ refpts,
               const int* __restrict__ qoff, int n_off,
               const int* __restrict__ perm,
               const f16* __restrict__ vp0, const f16* __restrict__ vp1,
               const f16* __restrict__ vp2, const f16* __restrict__ vp3,
               float* __restrict__ val_out) {
    __shared__ float sOff[GQPB][256];
    __shared__ float sAttn[GQPB][128];
    __shared__ int   sQ[GQPB];
    const int tid = threadIdx.x;

    const int bid = blockIdx.x;
    const int cpx = gridDim.x >> 3;
    const int swz = (bid & 7) * cpx + (bid >> 3);
    const int n0p = swz * GQPB;

    if (tid < GQPB) sQ[tid] = perm[n0p + tid];
    __syncthreads();

    {
        const int q = tid >> 6, i = tid & 63;
        const int nq = sQ[q];
        ((f32x4*)sOff[q])[i] = ((const f32x4*)(offs_all + (size_t)nq * 256))[i];
        if (i < 32) ((f32x4*)sAttn[q])[i] = ((const f32x4*)(logits_all + (size_t)nq * 128))[i];
    }
    __syncthreads();

    if (tid < GQPB * 8) {
        float* row = &sAttn[tid >> 3][(tid & 7) * 16];
        float m = -1e30f;
#pragma unroll
        for (int i = 0; i < 16; ++i) m = fmaxf(m, row[i]);
        float s = 0.f;
#pragma unroll
        for (int i = 0; i < 16; ++i) { const float e = expf(row[i] - m); row[i] = e; s += e; }
        const float inv = 1.f / s;
#pragma unroll
        for (int i = 0; i < 16; ++i) row[i] *= inv;
    }
    __syncthreads();

    const int q = tid >> 6, h = (tid >> 3) & 7;
    const int l8 = tid & 7, s = l8 & 3, jc = l8 >> 2;
    const int n = sQ[q];
    int b = 0;
    for (int i = 1; i < n_off; ++i) if (n >= qoff[i]) b = i;
    const float ri = refpts[2 * n], rj = refpts[2 * n + 1];
    const int s8 = s * 8;

    float acc[8];
#pragma unroll
    for (int j = 0; j < 8; ++j) acc[j] = 0.f;

#pragma unroll
    for (int l = 0; l < 4; ++l) {
        const int hw = (l == 0 ? 64 : (l == 1 ? 128 : (l == 2 ? 256 : 512)));
        const long hwsq = (long)hw * hw;
        const float sc = (float)hw * (1.0f / 512.0f);
        const f16* vbl = (l == 0 ? vp0 : (l == 1 ? vp1 : (l == 2 ? vp2 : vp3)));
        const f16* __restrict__ vb = vbl + (size_t)b * hwsq * 256 + (size_t)h * hwsq * 32 + s8;

        int   a0[4], a1[4];
        float w0v[4], w1v[4];
#pragma unroll
        for (int p = 0; p < 4; ++p) {
            const int oi = ((h * 4 + l) * 4 + p) * 2;
            const float fi = (ri + sOff[q][oi]) * sc;
            const float fj = (rj + sOff[q][oi + 1]) * sc;
            const float a = sAttn[q][(h * 4 + l) * 4 + p];
            const float sci = fmaxf(fi - 0.5f, 0.f);
            const float scj = fmaxf(fj - 0.5f, 0.f);
            const float fl_i = floorf(sci), fl_j = floorf(scj);
            const int i0 = (int)fl_i, j0 = (int)fl_j;
            const float fri = sci - fl_i, frj = scj - fl_j;
            const int i0c = min(i0, hw - 1), i1c = min(i0 + 1, hw - 1);
            const int j0c = min(j0, hw - 1), j1c = min(j0 + 1, hw - 1);
            const float uw = 1.f - fri, lw = 1.f - frj;
            const int jsel = jc ? j1c : j0c;
            a0[p] = (i0c * hw + jsel) * 32;
            a1[p] = (i1c * hw + jsel) * 32;
            w0v[p] = (jc ? uw * frj : uw * lw) * a;
            w1v[p] = (jc ? fri * frj : fri * lw) * a;
        }

        f16x8 buf[8];
#pragma unroll
        for (int p = 0; p < 4; ++p) {
            buf[2 * p]     = *(const f16x8*)(vb + (size_t)a0[p]);
            buf[2 * p + 1] = *(const f16x8*)(vb + (size_t)a1[p]);
        }
        asm volatile("" : "+v"(buf[0]), "+v"(buf[1]), "+v"(buf[2]), "+v"(buf[3]),
                          "+v"(buf[4]), "+v"(buf[5]), "+v"(buf[6]), "+v"(buf[7])
                        :: "memory");
#pragma unroll
        for (int p = 0; p < 4; ++p) {
            const float wa = w0v[p], wb = w1v[p];
#pragma unroll
            for (int j = 0; j < 8; ++j) {
                acc[j] = fmaf(wa, (float)buf[2 * p][j], acc[j]);
                acc[j] = fmaf(wb, (float)buf[2 * p + 1][j], acc[j]);
            }
        }
    }

#pragma unroll
    for (int j = 0; j < 8; ++j) acc[j] += __shfl_xor(acc[j], 4);

    if (jc == 0) {
        float* op = val_out + (size_t)n * 256 + h * 32 + s8;
        *(f32x4*)op       = (f32x4){acc[0], acc[1], acc[2], acc[3]};
        *(f32x4*)(op + 4) = (f32x4){acc[4], acc[5], acc[6], acc[7]};
    }
}

extern "C" void kernel_launch(void* const* d_in, const int* in_sizes, int n_in,
                              void* d_out, int out_size, void* d_ws, size_t ws_size,
                              hipStream_t stream) {
    const float* query  = (const float*)d_in[0];
    const int*   qoff   = (const int*)d_in[1];
    const float* refp   = (const float*)d_in[2];
    const float* v0     = (const float*)d_in[3];
    const float* v1     = (const float*)d_in[4];
    const float* v2     = (const float*)d_in[5];
    const float* v3     = (const float*)d_in[6];
    const float* W_off  = (const float*)d_in[7];
    const float* b_off  = (const float*)d_in[8];
    const float* W_attn = (const float*)d_in[9];
    const float* b_attn = (const float*)d_in[10];
    const float* W_val  = (const float*)d_in[11];
    const float* b_val  = (const float*)d_in[12];
    const float* W_out  = (const float*)d_in[13];
    const float* b_out  = (const float*)d_in[14];
    float* out = (float*)d_out;

    const int N = in_sizes[0] / 256;   // 16384
    const int n_off = in_sizes[1];     // 2

    float* P1off  = (float*)d_ws;                     // N*256 f32
    float* P1attn = P1off + (size_t)N * 256;          // N*128 f32
    int*   hist   = (int*)(P1attn + (size_t)N * 128); // NBINS
    int*   binptr = hist + NBINS;                     // NBINS
    int*   perm   = binptr + NBINS;                   // N

    const int M0 = 2 * 64 * 64, M1 = 2 * 128 * 128, M2 = 2 * 256 * 256, M3 = 2 * 512 * 512;
    const size_t base_b = (size_t)N * 256 * 4 + (size_t)N * 128 * 4 + (size_t)(2 * NBINS + N) * 4;

    hipMemsetAsync(hist, 0, NBINS * sizeof(int), stream);
    bin_hist<<<(N + 255) / 256, 256, 0, stream>>>(refp, hist, N);
    bin_scan<<<1, 256, 0, stream>>>(hist, binptr);
    bin_scatter<<<(N + 255) / 256, 256, 0, stream>>>(refp, binptr, perm, N);

    gemm_qproj<<<N / 32, 384, 0, stream>>>(query, W_off, b_off, W_attn, b_attn,
                                           P1off, P1attn);

    f16* wvF = (f16*)((char*)d_ws + base_b);
    f16* vp0 = wvF + 65536;
    f16* vp1 = vp0 + (size_t)M0 * 256;
    f16* vp2 = vp1 + (size_t)M1 * 256;
    f16* vp3 = vp2 + (size_t)M2 * 256;

    prep_wvF<<<256, 256, 0, stream>>>(W_val, wvF);
    proj_val_pipe2<<<2048, 256, 0, stream>>>(v0, v1, v2, v3, wvF, b_val,
                                             vp0, vp1, vp2, vp3);

    gather_vp<<<N / GQPB, 256, 0, stream>>>(P1off, P1attn, refp, qoff, n_off,
                                            perm, vp0, vp1, vp2, vp3, out);

    gemm_rb<256><<<N / 32, 256, 0, stream>>>(out, W_out, b_out, out);
}

// Round 23
// 452.437 us; speedup vs baseline: 1.0314x; 1.0314x over previous
//
#include <hip/hip_runtime.h>

// ---------------------------------------------------------------------------
// Sparse MS-Deformable Attention, f32 (+f16 projected value maps).
// Round 23: REVERT to r21 (best=453.8; r22's 2-deep pipeline lost 13us to
// VGPR-occupancy) + T5 s_setprio(1) around proj's MFMA cluster. proj's
// persistent blocks are phase-staggered per CU (intra-block barriers only)
// -- the regime where setprio pays (m191). Everything else byte-identical
// to r21.
// ---------------------------------------------------------------------------

typedef float f32x4 __attribute__((ext_vector_type(4)));
typedef _Float16 f16;
typedef f16 f16x8 __attribute__((ext_vector_type(8)));
typedef f16 f16x4 __attribute__((ext_vector_type(4)));

// Y[n, 0:M] = X[n, 0:256] @ W[256, M] + bias ; 32 rows/block, M threads.
// Safe in-place (Y==X): block stages its 32 rows to LDS before any write.
template<int M>
__global__ __launch_bounds__(M)
void gemm_rb(const float* __restrict__ X, const float* __restrict__ W,
             const float* __restrict__ bias, float* __restrict__ Y) {
    __shared__ float xt[32 * 256];
    const int tid = threadIdx.x;
    const long row0 = (long)blockIdx.x * 32;
    const float4* src = (const float4*)(X + row0 * 256);
    float4* dst4 = (float4*)xt;
    for (int i = tid; i < 32 * 64; i += M) dst4[i] = src[i];
    __syncthreads();

    constexpr int CG = M / 4;
    const int cg = tid % CG, qg = tid / CG;
    const int c0 = cg * 4, q0 = qg * 8;

    f32x4 acc[8];
#pragma unroll
    for (int qi = 0; qi < 8; ++qi) acc[qi] = (f32x4){0.f, 0.f, 0.f, 0.f};

    for (int k4 = 0; k4 < 64; ++k4) {
        f32x4 w[4];
#pragma unroll
        for (int r = 0; r < 4; ++r)
            w[r] = *(const f32x4*)&W[(size_t)(k4 * 4 + r) * M + c0];
        f32x4 xv[8];
#pragma unroll
        for (int qi = 0; qi < 8; ++qi)
            xv[qi] = *(const f32x4*)&xt[(q0 + qi) * 256 + k4 * 4];
#pragma unroll
        for (int qi = 0; qi < 8; ++qi) {
            f32x4 a = acc[qi];
            const f32x4 x = xv[qi];
            a.x = fmaf(x.x, w[0].x, a.x); a.y = fmaf(x.x, w[0].y, a.y);
            a.z = fmaf(x.x, w[0].z, a.z); a.w = fmaf(x.x, w[0].w, a.w);
            a.x = fmaf(x.y, w[1].x, a.x); a.y = fmaf(x.y, w[1].y, a.y);
            a.z = fmaf(x.y, w[1].z, a.z); a.w = fmaf(x.y, w[1].w, a.w);
            a.x = fmaf(x.z, w[2].x, a.x); a.y = fmaf(x.z, w[2].y, a.y);
            a.z = fmaf(x.z, w[2].z, a.z); a.w = fmaf(x.z, w[2].w, a.w);
            a.x = fmaf(x.w, w[3].x, a.x); a.y = fmaf(x.w, w[3].y, a.y);
            a.z = fmaf(x.w, w[3].z, a.z); a.w = fmaf(x.w, w[3].w, a.w);
            acc[qi] = a;
        }
    }

    const f32x4 bv = *(const f32x4*)&bias[c0];
#pragma unroll
    for (int qi = 0; qi < 8; ++qi) {
        f32x4 o = acc[qi];
        o.x += bv.x; o.y += bv.y; o.z += bv.z; o.w += bv.w;
        *(f32x4*)&Y[(size_t)(row0 + q0 + qi) * M + c0] = o;
    }
}

// ---- fused query projections: Y1[n,0:256]=X@W_off+b_off,
//      Y2[n,0:128]=X@W_attn+b_attn. 32 rows/block, 384 threads.
__global__ __launch_bounds__(384)
void gemm_qproj(const float* __restrict__ X,
                const float* __restrict__ W_off, const float* __restrict__ b_off,
                const float* __restrict__ W_attn, const float* __restrict__ b_attn,
                float* __restrict__ Y1, float* __restrict__ Y2) {
    __shared__ float xt[32 * 260];
    const int tid = threadIdx.x;
    const long row0 = (long)blockIdx.x * 32;
    const float4* src = (const float4*)(X + row0 * 256);
    for (int i = tid; i < 32 * 64; i += 384) {
        const int r = i >> 6, c4 = i & 63;
        *(float4*)(xt + r * 260 + c4 * 4) = src[i];
    }
    __syncthreads();

    const int cg = tid % 96, qg = tid / 96;
    const int c0 = cg * 4, q0 = qg * 8;
    const bool off_part = (c0 < 256);
    const float* Wp = off_part ? (W_off + c0) : (W_attn + (c0 - 256));
    const float* bp = off_part ? (b_off + c0) : (b_attn + (c0 - 256));
    const int ldW = off_part ? 256 : 128;
    float* Yp = off_part ? (Y1 + c0) : (Y2 + (c0 - 256));

    f32x4 acc[8];
#pragma unroll
    for (int qi = 0; qi < 8; ++qi) acc[qi] = (f32x4){0.f, 0.f, 0.f, 0.f};

    for (int k4 = 0; k4 < 64; ++k4) {
        f32x4 w[4];
#pragma unroll
        for (int r = 0; r < 4; ++r)
            w[r] = *(const f32x4*)&Wp[(size_t)(k4 * 4 + r) * ldW];
        f32x4 xv[8];
#pragma unroll
        for (int qi = 0; qi < 8; ++qi)
            xv[qi] = *(const f32x4*)&xt[(q0 + qi) * 260 + k4 * 4];
#pragma unroll
        for (int qi = 0; qi < 8; ++qi) {
            f32x4 a = acc[qi];
            const f32x4 x = xv[qi];
            a.x = fmaf(x.x, w[0].x, a.x); a.y = fmaf(x.x, w[0].y, a.y);
            a.z = fmaf(x.x, w[0].z, a.z); a.w = fmaf(x.x, w[0].w, a.w);
            a.x = fmaf(x.y, w[1].x, a.x); a.y = fmaf(x.y, w[1].y, a.y);
            a.z = fmaf(x.y, w[1].z, a.z); a.w = fmaf(x.y, w[1].w, a.w);
            a.x = fmaf(x.z, w[2].x, a.x); a.y = fmaf(x.z, w[2].y, a.y);
            a.z = fmaf(x.z, w[2].z, a.z); a.w = fmaf(x.z, w[2].w, a.w);
            a.x = fmaf(x.w, w[3].x, a.x); a.y = fmaf(x.w, w[3].y, a.y);
            a.z = fmaf(x.w, w[3].z, a.z); a.w = fmaf(x.w, w[3].w, a.w);
            acc[qi] = a;
        }
    }

    const f32x4 bv = *(const f32x4*)bp;
#pragma unroll
    for (int qi = 0; qi < 8; ++qi) {
        f32x4 o = acc[qi];
        o.x += bv.x; o.y += bv.y; o.z += bv.z; o.w += bv.w;
        *(f32x4*)&Yp[(size_t)(row0 + q0 + qi) * ldW] = o;
    }
}

// ---- spatial binning ----
#define NBINS 4096

__device__ __forceinline__ int bin_of(float ri, float rj) {
    int bi = (int)ri >> 3, bj = (int)rj >> 3;
    bi = min(63, max(0, bi)); bj = min(63, max(0, bj));
    return bi * 64 + bj;
}

__global__ void bin_hist(const float* __restrict__ refp, int* __restrict__ hist, int N) {
    const int n = blockIdx.x * blockDim.x + threadIdx.x;
    if (n < N) atomicAdd(&hist[bin_of(refp[2 * n], refp[2 * n + 1])], 1);
}

__global__ __launch_bounds__(256)
void bin_scan(const int* __restrict__ hist, int* __restrict__ binptr) {
    __shared__ int part[256];
    const int t = threadIdx.x;
    int vals[16], excl[16], run = 0;
#pragma unroll
    for (int i = 0; i < 16; ++i) { vals[i] = hist[t * 16 + i]; }
#pragma unroll
    for (int i = 0; i < 16; ++i) { excl[i] = run; run += vals[i]; }
    part[t] = run;
    __syncthreads();
    int off = 0;
    for (int i = 0; i < t; ++i) off += part[i];
#pragma unroll
    for (int i = 0; i < 16; ++i) binptr[t * 16 + i] = off + excl[i];
}

__global__ void bin_scatter(const float* __restrict__ refp, int* __restrict__ binptr,
                            int* __restrict__ perm, int N) {
    const int n = blockIdx.x * blockDim.x + threadIdx.x;
    if (n < N) {
        const int b = bin_of(refp[2 * n], refp[2 * n + 1]);
        const int pos = atomicAdd(&binptr[b], 1);
        perm[pos] = n;
    }
}

// ---- W_val swizzle into MFMA-fragment order ----
__global__ __launch_bounds__(256)
void prep_wvF(const float* __restrict__ W, f16* __restrict__ wvF) {
    const int k = blockIdx.x, n = threadIdx.x;
    const int ks = k >> 5, kg = (k >> 3) & 3, j = k & 7;
    const int tile = n >> 4, l15 = n & 15;
    const int lane = (kg << 4) | l15;
    wvF[((size_t)(ks * 16 + tile) * 512) + lane * 8 + j] = (f16)W[(size_t)k * 256 + n];
}

// ---- persistent 1-deep pipelined MFMA f16 projection, 32-px tiles,
//      head-planar, LDS-staged coalesced copy-out. (r21 + setprio)
#define NT_PROJ 21760
__global__ __launch_bounds__(256)
void proj_val_pipe(const float* __restrict__ v0, const float* __restrict__ v1,
                   const float* __restrict__ v2, const float* __restrict__ v3,
                   const f16* __restrict__ wvF, const float* __restrict__ bval,
                   f16* __restrict__ vp0, f16* __restrict__ vp1,
                   f16* __restrict__ vp2, f16* __restrict__ vp3) {
    __shared__ f16 At[32][264];
    const int tid = threadIdx.x;
    const int wave = tid >> 6, lane = tid & 63;
    const int l15 = lane & 15, kg = lane >> 4;
    const int G = gridDim.x;

#define TILE_INFO(T, V, VP, PX0, HWSQ) do {                                    \
    if ((T) < 256)        { V = v0; VP = vp0; PX0 = (long)(T) * 32;          HWSQ = 4096;   } \
    else if ((T) < 1280)  { V = v1; VP = vp1; PX0 = (long)((T) - 256) * 32;  HWSQ = 16384;  } \
    else if ((T) < 5376)  { V = v2; VP = vp2; PX0 = (long)((T) - 1280) * 32; HWSQ = 65536;  } \
    else                  { V = v3; VP = vp3; PX0 = (long)((T) - 5376) * 32; HWSQ = 262144; } \
} while (0)

    int t = blockIdx.x;
    if (t >= NT_PROJ) return;

    float4 st[8];
    {
        const float* V; f16* VP; long px0, hwsq;
        TILE_INFO(t, V, VP, px0, hwsq);
#pragma unroll
        for (int i = 0; i < 8; ++i)
            st[i] = *(const float4*)(V + (px0 + wave + i * 4) * 256 + lane * 4);
    }

    for (; t < NT_PROJ; t += G) {
        // 1. convert staged regs -> LDS (vmcnt wait lands here; covered by
        //    the previous iteration's MFMA + epilogue)
        __syncthreads();   // prior copy-out done reading At (no-op first iter)
#pragma unroll
        for (int i = 0; i < 8; ++i) {
            const int px = wave + i * 4;
            f16x4 h4 = {(f16)st[i].x, (f16)st[i].y, (f16)st[i].z, (f16)st[i].w};
            *(f16x4*)(&At[px][lane * 4]) = h4;
        }
        __syncthreads();

        // 2. issue NEXT tile's loads; fence pins them before the ds_reads.
        const int tn = t + G;
        if (tn < NT_PROJ) {
            const float* Vn; f16* VPn; long px0n, hwsqn;
            TILE_INFO(tn, Vn, VPn, px0n, hwsqn);
#pragma unroll
            for (int i = 0; i < 8; ++i)
                st[i] = *(const float4*)(Vn + (px0n + wave + i * 4) * 256 + lane * 4);
            asm volatile("" ::: "memory");
        }

        // 3. MFMA (setprio: persistent blocks are phase-staggered per CU)
        f32x4 acc[2][4];
#pragma unroll
        for (int a = 0; a < 2; ++a)
#pragma unroll
            for (int b = 0; b < 4; ++b) acc[a][b] = (f32x4){0.f, 0.f, 0.f, 0.f};

        __builtin_amdgcn_s_setprio(1);
#pragma unroll
        for (int ks = 0; ks < 8; ++ks) {
            f16x8 wf[4];
#pragma unroll
            for (int ct = 0; ct < 4; ++ct)
                wf[ct] = *(const f16x8*)(wvF + ((size_t)(ks * 16 + wave * 4 + ct) * 512) + lane * 8);
            f16x8 vf[2];
#pragma unroll
            for (int pt = 0; pt < 2; ++pt)
                vf[pt] = *(const f16x8*)(&At[pt * 16 + l15][ks * 32 + kg * 8]);
#pragma unroll
            for (int pt = 0; pt < 2; ++pt)
#pragma unroll
                for (int ct = 0; ct < 4; ++ct)
                    acc[pt][ct] = __builtin_amdgcn_mfma_f32_16x16x32_f16(wf[ct], vf[pt], acc[pt][ct], 0, 0, 0);
        }
        __builtin_amdgcn_s_setprio(0);

        // 4. acc + bias -> LDS (all waves done reading At)
        __syncthreads();
#pragma unroll
        for (int ct = 0; ct < 4; ++ct) {
            const int chb = wave * 64 + ct * 16 + kg * 4;
            const float4 bv = *(const float4*)(bval + chb);
#pragma unroll
            for (int pt = 0; pt < 2; ++pt) {
                f16x4 o = {(f16)(acc[pt][ct].x + bv.x), (f16)(acc[pt][ct].y + bv.y),
                           (f16)(acc[pt][ct].z + bv.z), (f16)(acc[pt][ct].w + bv.w)};
                *(f16x4*)(&At[pt * 16 + l15][chb]) = o;
            }
        }
        __syncthreads();

        // 5. coalesced head-planar copy-out (1KB runs per half-wave)
        {
            const float* Vc; f16* VP; long px0, hwsq;
            TILE_INFO(t, Vc, VP, px0, hwsq);
            const long bt = (px0 >= hwsq) ? 1 : 0;
            const long pxb = px0 - bt * hwsq;
            f16* base = VP + (size_t)bt * hwsq * 256;
#pragma unroll
            for (int i = 0; i < 4; ++i) {
                const int c2 = i * 256 + tid;
                const int hh = c2 >> 7;
                const int rem = c2 & 127;
                const int px = rem >> 2;
                const int sub = rem & 3;
                *(f16x8*)(base + (size_t)hh * hwsq * 32 + (pxb + px) * 32 + sub * 8) =
                    *(const f16x8*)(&At[px][hh * 32 + sub * 8]);
            }
        }
    }
#undef TILE_INFO
}

// ---- gather from head-planar vp (byte-identical to r19/r21) ----------------
#define GQPB 4
__global__ __launch_bounds__(256)
void gather_vp(const float* __restrict__ offs_all,
               const float* __restrict__ logits_all,
               const float* __restrict__ refpts,
               const int* __restrict__ qoff, int n_off,
               const int* __restrict__ perm,
               const f16* __restrict__ vp0, const f16* __restrict__ vp1,
               const f16* __restrict__ vp2, const f16* __restrict__ vp3,
               float* __restrict__ val_out) {
    __shared__ float sOff[GQPB][256];
    __shared__ float sAttn[GQPB][128];
    __shared__ int   sQ[GQPB];
    const int tid = threadIdx.x;

    const int bid = blockIdx.x;
    const int cpx = gridDim.x >> 3;
    const int swz = (bid & 7) * cpx + (bid >> 3);
    const int n0p = swz * GQPB;

    if (tid < GQPB) sQ[tid] = perm[n0p + tid];
    __syncthreads();

    {
        const int q = tid >> 6, i = tid & 63;
        const int nq = sQ[q];
        ((f32x4*)sOff[q])[i] = ((const f32x4*)(offs_all + (size_t)nq * 256))[i];
        if (i < 32) ((f32x4*)sAttn[q])[i] = ((const f32x4*)(logits_all + (size_t)nq * 128))[i];
    }
    __syncthreads();

    if (tid < GQPB * 8) {
        float* row = &sAttn[tid >> 3][(tid & 7) * 16];
        float m = -1e30f;
#pragma unroll
        for (int i = 0; i < 16; ++i) m = fmaxf(m, row[i]);
        float s = 0.f;
#pragma unroll
        for (int i = 0; i < 16; ++i) { const float e = expf(row[i] - m); row[i] = e; s += e; }
        const float inv = 1.f / s;
#pragma unroll
        for (int i = 0; i < 16; ++i) row[i] *= inv;
    }
    __syncthreads();

    const int q = tid >> 6, h = (tid >> 3) & 7;
    const int l8 = tid & 7, s = l8 & 3, jc = l8 >> 2;
    const int n = sQ[q];
    int b = 0;
    for (int i = 1; i < n_off; ++i) if (n >= qoff[i]) b = i;
    const float ri = refpts[2 * n], rj = refpts[2 * n + 1];
    const int s8 = s * 8;

    float acc[8];
#pragma unroll
    for (int j = 0; j < 8; ++j) acc[j] = 0.f;

#pragma unroll
    for (int l = 0; l < 4; ++l) {
        const int hw = (l == 0 ? 64 : (l == 1 ? 128 : (l == 2 ? 256 : 512)));
        const long hwsq = (long)hw * hw;
        const float sc = (float)hw * (1.0f / 512.0f);
        const f16* vbl = (l == 0 ? vp0 : (l == 1 ? vp1 : (l == 2 ? vp2 : vp3)));
        const f16* __restrict__ vb = vbl + (size_t)b * hwsq * 256 + (size_t)h * hwsq * 32 + s8;

        int   a0[4], a1[4];
        float w0v[4], w1v[4];
#pragma unroll
        for (int p = 0; p < 4; ++p) {
            const int oi = ((h * 4 + l) * 4 + p) * 2;
            const float fi = (ri + sOff[q][oi]) * sc;
            const float fj = (rj + sOff[q][oi + 1]) * sc;
            const float a = sAttn[q][(h * 4 + l) * 4 + p];
            const float sci = fmaxf(fi - 0.5f, 0.f);
            const float scj = fmaxf(fj - 0.5f, 0.f);
            const float fl_i = floorf(sci), fl_j = floorf(scj);
            const int i0 = (int)fl_i, j0 = (int)fl_j;
            const float fri = sci - fl_i, frj = scj - fl_j;
            const int i0c = min(i0, hw - 1), i1c = min(i0 + 1, hw - 1);
            const int j0c = min(j0, hw - 1), j1c = min(j0 + 1, hw - 1);
            const float uw = 1.f - fri, lw = 1.f - frj;
            const int jsel = jc ? j1c : j0c;
            a0[p] = (i0c * hw + jsel) * 32;
            a1[p] = (i1c * hw + jsel) * 32;
            w0v[p] = (jc ? uw * frj : uw * lw) * a;
            w1v[p] = (jc ? fri * frj : fri * lw) * a;
        }

        f16x8 buf[8];
#pragma unroll
        for (int p = 0; p < 4; ++p) {
            buf[2 * p]     = *(const f16x8*)(vb + (size_t)a0[p]);
            buf[2 * p + 1] = *(const f16x8*)(vb + (size_t)a1[p]);
        }
        asm volatile("" : "+v"(buf[0]), "+v"(buf[1]), "+v"(buf[2]), "+v"(buf[3]),
                          "+v"(buf[4]), "+v"(buf[5]), "+v"(buf[6]), "+v"(buf[7])
                        :: "memory");
#pragma unroll
        for (int p = 0; p < 4; ++p) {
            const float wa = w0v[p], wb = w1v[p];
#pragma unroll
            for (int j = 0; j < 8; ++j) {
                acc[j] = fmaf(wa, (float)buf[2 * p][j], acc[j]);
                acc[j] = fmaf(wb, (float)buf[2 * p + 1][j], acc[j]);
            }
        }
    }

#pragma unroll
    for (int j = 0; j < 8; ++j) acc[j] += __shfl_xor(acc[j], 4);

    if (jc == 0) {
        float* op = val_out + (size_t)n * 256 + h * 32 + s8;
        *(f32x4*)op       = (f32x4){acc[0], acc[1], acc[2], acc[3]};
        *(f32x4*)(op + 4) = (f32x4){acc[4], acc[5], acc[6], acc[7]};
    }
}

extern "C" void kernel_launch(void* const* d_in, const int* in_sizes, int n_in,
                              void* d_out, int out_size, void* d_ws, size_t ws_size,
                              hipStream_t stream) {
    const float* query  = (const float*)d_in[0];
    const int*   qoff   = (const int*)d_in[1];
    const float* refp   = (const float*)d_in[2];
    const float* v0     = (const float*)d_in[3];
    const float* v1     = (const float*)d_in[4];
    const float* v2     = (const float*)d_in[5];
    const float* v3     = (const float*)d_in[6];
    const float* W_off  = (const float*)d_in[7];
    const float* b_off  = (const float*)d_in[8];
    const float* W_attn = (const float*)d_in[9];
    const float* b_attn = (const float*)d_in[10];
    const float* W_val  = (const float*)d_in[11];
    const float* b_val  = (const float*)d_in[12];
    const float* W_out  = (const float*)d_in[13];
    const float* b_out  = (const float*)d_in[14];
    float* out = (float*)d_out;

    const int N = in_sizes[0] / 256;   // 16384
    const int n_off = in_sizes[1];     // 2

    float* P1off  = (float*)d_ws;                     // N*256 f32
    float* P1attn = P1off + (size_t)N * 256;          // N*128 f32
    int*   hist   = (int*)(P1attn + (size_t)N * 128); // NBINS
    int*   binptr = hist + NBINS;                     // NBINS
    int*   perm   = binptr + NBINS;                   // N

    const int M0 = 2 * 64 * 64, M1 = 2 * 128 * 128, M2 = 2 * 256 * 256, M3 = 2 * 512 * 512;
    const size_t base_b = (size_t)N * 256 * 4 + (size_t)N * 128 * 4 + (size_t)(2 * NBINS + N) * 4;

    hipMemsetAsync(hist, 0, NBINS * sizeof(int), stream);
    bin_hist<<<(N + 255) / 256, 256, 0, stream>>>(refp, hist, N);
    bin_scan<<<1, 256, 0, stream>>>(hist, binptr);
    bin_scatter<<<(N + 255) / 256, 256, 0, stream>>>(refp, binptr, perm, N);

    gemm_qproj<<<N / 32, 384, 0, stream>>>(query, W_off, b_off, W_attn, b_attn,
                                           P1off, P1attn);

    f16* wvF = (f16*)((char*)d_ws + base_b);
    f16* vp0 = wvF + 65536;
    f16* vp1 = vp0 + (size_t)M0 * 256;
    f16* vp2 = vp1 + (size_t)M1 * 256;
    f16* vp3 = vp2 + (size_t)M2 * 256;

    prep_wvF<<<256, 256, 0, stream>>>(W_val, wvF);
    proj_val_pipe<<<2048, 256, 0, stream>>>(v0, v1, v2, v3, wvF, b_val,
                                            vp0, vp1, vp2, vp3);

    gather_vp<<<N / GQPB, 256, 0, stream>>>(P1off, P1attn, refp, qoff, n_off,
                                            perm, vp0, vp1, vp2, vp3, out);

    gemm_rb<256><<<N / 32, 256, 0, stream>>>(out, W_out, b_out, out);
}